// Round 4
// baseline (521.984 us; speedup 1.0000x reference)
//
#include <hip/hip_runtime.h>
#include <math.h>

#define ST_AGG 1ull
#define ST_PRE 2ull

// ---------------- wave-parallel two-level select (runs in ONE block) ----------------
// hist = 65536 bins viewed as 256 chunks x 256. Finds bucket containing ascending rank q.
// Reads use agent-scope atomic loads: hist was written by device atomics in the SAME
// kernel (last-block fusion) -- plain loads could hit a stale per-XCD L2 line.
__device__ __forceinline__ void block_select(
    const unsigned* __restrict__ hist, unsigned q,
    unsigned* __restrict__ outB, unsigned* __restrict__ outRem) {
  __shared__ unsigned sc[256];
  __shared__ unsigned sres[2];
  int t = threadIdx.x;
  {  // level 1: per-thread row sum (128 x 8B coherent loads), then parallel scan+search
    const unsigned long long* hp = (const unsigned long long*)(hist + t * 256);
    unsigned s = 0;
    #pragma unroll 8
    for (int j = 0; j < 128; j++) {
      unsigned long long v =
          __hip_atomic_load(&hp[j], __ATOMIC_RELAXED, __HIP_MEMORY_SCOPE_AGENT);
      s += (unsigned)v + (unsigned)(v >> 32);
    }
    sc[t] = s;
    unsigned val = s;
    __syncthreads();
    for (int st = 1; st < 256; st <<= 1) {
      unsigned a = (t >= st) ? sc[t - st] : 0u;
      __syncthreads();
      sc[t] += a;
      __syncthreads();
    }
    unsigned incl = sc[t], excl = incl - val;
    if (q >= excl && q < incl) { sres[0] = (unsigned)t; sres[1] = q - excl; }
  }
  __syncthreads();
  unsigned chunk = sres[0], rem = sres[1];
  {  // level 2: 256 bins of the chosen chunk
    unsigned v = __hip_atomic_load(&hist[chunk * 256 + t], __ATOMIC_RELAXED,
                                   __HIP_MEMORY_SCOPE_AGENT);
    __syncthreads();
    sc[t] = v;
    unsigned val = v;
    __syncthreads();
    for (int st = 1; st < 256; st <<= 1) {
      unsigned a = (t >= st) ? sc[t - st] : 0u;
      __syncthreads();
      sc[t] += a;
      __syncthreads();
    }
    unsigned incl = sc[t], excl = incl - val;
    if (rem >= excl && rem < incl) {
      *outB = chunk * 256 + t;
      *outRem = rem - excl;
    }
  }
}

// ---------------- scores + hi16 histogram + last-block select1 (fused) ----------------
// Precision: fp64 products of fp32 inputs are EXACT; only fp64 sum association differs
// from the verified original (~1e-16 relative) -> fp32 scores cannot flip. (Proven
// passing in round 3.)
__global__ __launch_bounds__(256) void scores_hist_kernel(
    const float* __restrict__ x, const float* __restrict__ w,
    const float* __restrict__ bptr, int N, int F, unsigned* __restrict__ scores,
    unsigned* __restrict__ hist, unsigned qconst, unsigned* __restrict__ sel,
    unsigned* __restrict__ doneCnt) {
  __shared__ float tX[64 * 128];     // 32 KB tile
  __shared__ double sPart[4 * 64];   // [seg][row]
  __shared__ float wS[128];
  __shared__ unsigned sLast;
  int t = threadIdx.x;
  int blockBase = blockIdx.x * 256;
  if (t < 128) wS[t] = w[t];
  __syncthreads();
  int row = t & 63, seg = t >> 6;
  float4 wreg[8];
  {
    const float4* w4 = (const float4*)(wS + seg * 32);
    #pragma unroll
    for (int k = 0; k < 8; k++) wreg[k] = w4[k];
  }
  double bias = (double)bptr[0];
  for (int tile = 0; tile < 4; tile++) {
    int rowBase = blockBase + tile * 64;
    {  // cooperative coalesced load: 2048 float4, 8 per thread
      const float4* src = (const float4*)(x + (size_t)rowBase * 128);
      float4* dst = (float4*)tX;
      #pragma unroll
      for (int k = 0; k < 8; k++) {
        int idx = t + k * 256;
        int grow = rowBase + (idx >> 5);   // 32 float4 per row
        float4 v = make_float4(0.f, 0.f, 0.f, 0.f);
        if (grow < N) v = src[idx];
        dst[idx] = v;
      }
    }
    __syncthreads();
    {  // 32-elem fp64 partial dot per thread
      const float4* xr = (const float4*)(tX + row * 128 + seg * 32);
      double acc = 0.0;
      #pragma unroll
      for (int k = 0; k < 8; k++) {
        float4 xv = xr[k];
        float4 wv = wreg[k];
        acc += (double)xv.x * (double)wv.x;
        acc += (double)xv.y * (double)wv.y;
        acc += (double)xv.z * (double)wv.z;
        acc += (double)xv.w * (double)wv.w;
      }
      sPart[seg * 64 + row] = acc;
    }
    __syncthreads();
    if (t < 64) {  // wave 0: 64 sigmoids in parallel
      int node = rowBase + t;
      if (node < N) {
        double z = sPart[t] + sPart[64 + t] + sPart[128 + t] + sPart[192 + t] + bias;
        double s = 1.0 / (1.0 + exp(-z));
        unsigned bits = __float_as_uint((float)s);  // positive floats: order-monotone
        scores[node] = bits;
        atomicAdd(&hist[bits >> 16], 1u);
      }
    }
    __syncthreads();
  }
  // last block to finish runs select1 (hist is complete once doneCnt == gridDim)
  __threadfence();
  if (t == 0) sLast = (atomicAdd(doneCnt, 1u) == gridDim.x - 1u) ? 1u : 0u;
  __syncthreads();
  if (sLast) block_select(hist, qconst, sel + 0, sel + 1);
}

// ---------------- pass-1 histogram (lo16 within selected hi16) + last-block select2 ----
__global__ __launch_bounds__(256) void hist2_kernel(
    const unsigned* __restrict__ scores, int N, const unsigned* __restrict__ sel,
    unsigned* __restrict__ hist, unsigned* __restrict__ selOut,
    unsigned* __restrict__ doneCnt) {
  __shared__ unsigned sLast;
  int i = blockIdx.x * 256 + threadIdx.x;
  if (i < N) {
    unsigned bits = scores[i];
    if ((bits >> 16) == sel[0]) atomicAdd(&hist[bits & 0xFFFFu], 1u);
  }
  __threadfence();
  if (threadIdx.x == 0) sLast = (atomicAdd(doneCnt, 1u) == gridDim.x - 1u) ? 1u : 0u;
  __syncthreads();
  if (sLast) block_select(hist, sel[1], selOut + 0, selOut + 1);
}

// ---------------- wave-parallel decoupled lookback (wave 0 only) ----------------
__device__ __forceinline__ unsigned lookback_exclusive(
    unsigned long long* status, int bid, int lane) {
  unsigned excl = 0;
  int j = bid - 1;
  for (;;) {
    int idx = j - lane;
    unsigned long long st;
    if (idx >= 0) {
      do {
        st = __hip_atomic_load(&status[idx], __ATOMIC_RELAXED, __HIP_MEMORY_SCOPE_AGENT);
      } while ((st >> 32) == 0ull);
    } else {
      st = (ST_PRE << 32);  // virtual PREFIX=0 below index 0
    }
    int isPre = ((st >> 32) == ST_PRE);
    unsigned long long preb = __ballot(isPre);
    int p = __ffsll(preb) - 1;
    unsigned contrib = (p < 0 || lane <= p) ? (unsigned)st : 0u;
    for (int off = 32; off > 0; off >>= 1)
      contrib += __shfl_down(contrib, off, 64);
    excl += __shfl(contrib, 0, 64);
    if (p >= 0) return excl;
    j -= 64;
  }
}

__device__ __forceinline__ void publish_status(
    unsigned long long* status, int bid, unsigned long long st, unsigned v) {
  __hip_atomic_store(&status[bid], (st << 32) | (unsigned long long)v,
                     __ATOMIC_RELAXED, __HIP_MEMORY_SCOPE_AGENT);
}

// ---------------- node compaction + fused new_x gather, one pass ----------------
__global__ __launch_bounds__(256) void node_compact(
    const unsigned* __restrict__ scores, const unsigned* __restrict__ sel,
    const float* __restrict__ x, int N, int F, int n_keep,
    unsigned* __restrict__ ticket, unsigned long long* __restrict__ status,
    int* __restrict__ map, float* __restrict__ out_pool, float* __restrict__ outx) {
  __shared__ unsigned sBid;
  __shared__ unsigned wv[4];
  __shared__ unsigned sExcl;
  __shared__ int sSrc[256];       // kept node: source node id (dense, block order)
  int t = threadIdx.x;
  if (t == 0) sBid = atomicAdd(ticket, 1u);   // tickets follow execution-start order
  __syncthreads();
  int bid = (int)sBid;
  int i = bid * 256 + t;
  unsigned T = (sel[0] << 16) | sel[2];
  int m = (i < N) && (scores[i] >= T);
  unsigned long long bal = __ballot(m);
  int lane = t & 63, wave = t >> 6;
  if (lane == 0) wv[wave] = (unsigned)__popcll(bal);
  __syncthreads();
  unsigned agg = wv[0] + wv[1] + wv[2] + wv[3];
  if (wave == 0) {
    if (lane == 0 && bid > 0) publish_status(status, bid, ST_AGG, agg);
    unsigned excl = (bid > 0) ? lookback_exclusive(status, bid, lane) : 0u;
    if (lane == 0) {
      publish_status(status, bid, ST_PRE, excl + agg);
      sExcl = excl;
    }
  }
  __syncthreads();
  unsigned wpre = 0;
  for (int k = 0; k < wave; k++) wpre += wv[k];
  unsigned li = wpre + (unsigned)__popcll(bal & ((1ull << lane) - 1ull));
  if (i < N) {
    int mv = -1;
    if (m) {
      unsigned pre = sExcl + li;
      if (pre < (unsigned)n_keep) {   // tie insurance; order = ascending node index
        mv = (int)pre;
        out_pool[pre] = (float)i;
        sSrc[li] = i;
      }
    }
    map[i] = mv;
  }
  __syncthreads();
  // kept entries form a dense prefix (ranks sExcl+k); cap at n_keep
  unsigned lim = agg;
  if (sExcl + agg > (unsigned)n_keep)
    lim = ((unsigned)n_keep > sExcl) ? ((unsigned)n_keep - sExcl) : 0u;
  // block-cooperative new_x row copy: 32 threads per 512B row, one float4 each
  for (int k = t >> 5; k < (int)lim; k += 8) {
    const float4* s4 = (const float4*)(x + (size_t)sSrc[k] * F);
    float4* d4 = (float4*)(outx + (size_t)(sExcl + (unsigned)k) * F);
    d4[t & 31] = s4[t & 31];
  }
}

// ---------------- edge compaction: 1024 edges/block, LDS-staged coalesced writes -------
__global__ __launch_bounds__(256) void edge_compact(
    const int* __restrict__ ei, const int* __restrict__ map, int E, int Ek, int Fe,
    const float* __restrict__ attr,
    unsigned* __restrict__ ticket, unsigned long long* __restrict__ status,
    float* __restrict__ out,
    size_t o_ei, size_t o_eio, size_t o_attr, size_t o_pe) {
  __shared__ unsigned sBid;
  __shared__ unsigned wv[4];
  __shared__ unsigned sExcl;
  __shared__ int sE[1024];                      // kept edge ids, dense; rank = sExcl + k
  __shared__ float sA[1024], sB[1024], sMA[1024], sMB[1024];  // staged value streams
  int t = threadIdx.x;
  if (t == 0) sBid = atomicAdd(ticket, 1u);
  __syncthreads();
  int bid = (int)sBid;
  int e0 = bid * 1024 + t * 4;   // E % 4 == 0 -> a thread's 4 edges never straddle E
  int m[4] = {0, 0, 0, 0};
  int av[4], bv[4], mav[4], mbv[4];
  unsigned c = 0;
  if (e0 < E) {
    int4 a4 = ((const int4*)ei)[(size_t)bid * 256 + t];
    int4 b4 = ((const int4*)(ei + E))[(size_t)bid * 256 + t];
    av[0] = a4.x; av[1] = a4.y; av[2] = a4.z; av[3] = a4.w;
    bv[0] = b4.x; bv[1] = b4.y; bv[2] = b4.z; bv[3] = b4.w;
    #pragma unroll
    for (int j = 0; j < 4; j++) {
      mav[j] = map[av[j]];
      mbv[j] = map[bv[j]];
      m[j] = (mav[j] >= 0) && (mbv[j] >= 0);
      c += (unsigned)m[j];
    }
    float4 pe4 = make_float4((float)m[0], (float)m[1], (float)m[2], (float)m[3]);
    *(float4*)(out + o_pe + e0) = pe4;
  }
  // wave-level exclusive scan of per-thread counts
  int lane = t & 63, wave = t >> 6;
  unsigned incl = c;
  #pragma unroll
  for (int off = 1; off < 64; off <<= 1) {
    unsigned u = __shfl_up(incl, off, 64);
    if (lane >= off) incl += u;
  }
  if (lane == 63) wv[wave] = incl;
  __syncthreads();
  unsigned agg = wv[0] + wv[1] + wv[2] + wv[3];
  if (wave == 0) {
    if (lane == 0 && bid > 0) publish_status(status, bid, ST_AGG, agg);
    unsigned excl = (bid > 0) ? lookback_exclusive(status, bid, lane) : 0u;
    if (lane == 0) {
      publish_status(status, bid, ST_PRE, excl + agg);
      sExcl = excl;
    }
  }
  __syncthreads();
  unsigned wpre = 0;
  for (int k = 0; k < wave; k++) wpre += wv[k];
  unsigned r = wpre + (incl - c);       // block-local rank of this thread's first kept edge
  if (e0 < E) {
    #pragma unroll
    for (int j = 0; j < 4; j++) {
      if (m[j]) {
        sE[r]  = e0 + j;
        sA[r]  = (float)av[j];
        sB[r]  = (float)bv[j];
        sMA[r] = (float)mav[j];
        sMB[r] = (float)mbv[j];
        r++;
      }
    }
  }
  __syncthreads();
  // lane-consecutive coalesced writes of the 4 dense streams
  for (int k = t; k < (int)agg; k += 256) {
    unsigned p = sExcl + (unsigned)k;
    out[o_ei + p]              = sA[k];
    out[o_ei + (size_t)Ek + p] = sB[k];
    out[o_eio + p]              = sMA[k];
    out[o_eio + (size_t)Ek + p] = sMB[k];
  }
  // block-cooperative attr copy: 8 threads per 128B row, one float4 each
  for (int k = t >> 3; k < (int)agg; k += 32) {
    const float4* src = (const float4*)(attr + (size_t)sE[k] * Fe);
    float4* dst = (float4*)(out + o_attr + (size_t)(sExcl + (unsigned)k) * Fe);
    dst[t & 7] = src[t & 7];
  }
}

extern "C" void kernel_launch(void* const* d_in, const int* in_sizes, int n_in,
                              void* d_out, int out_size, void* d_ws, size_t ws_size,
                              hipStream_t stream) {
  const int F  = in_sizes[2];        // 128
  const int E  = in_sizes[4] / 2;    // 1,600,000
  const int N  = in_sizes[0] / F;    // 100,000
  const int Fe = in_sizes[1] / E;    // 32
  const int n_keep = N / 2;          // int(N * K_FRAC), K_FRAC = 0.5
  const unsigned q = (unsigned)(N - n_keep - 1);  // kth-1 (0-based ascending order stat)
  // out_size = n_keep*F + 2Ek + 2Ek + Ek*Fe + n_keep + E  =>  solve for Ek
  const int Ek = (int)(((long long)out_size - (long long)n_keep * F - n_keep - E) / (4 + Fe));

  const float* x    = (const float*)d_in[0];
  const float* attr = (const float*)d_in[1];
  const float* w    = (const float*)d_in[2];
  const float* b    = (const float*)d_in[3];
  const int*   ei   = (const int*)d_in[4];
  float*       out  = (float*)d_out;

  const size_t o_newx = 0;
  const size_t o_ei   = (size_t)n_keep * F;
  const size_t o_eio  = o_ei + 2 * (size_t)Ek;
  const size_t o_attr = o_eio + 2 * (size_t)Ek;
  const size_t o_pool = o_attr + (size_t)Ek * Fe;
  const size_t o_pe   = o_pool + (size_t)n_keep;

  // workspace carve (256B aligned regions)
  char* wsb = (char*)d_ws;
  size_t off = 0;
  auto carve = [&](size_t bytes) -> void* {
    void* p = wsb + off;
    off = (off + bytes + 255) & ~(size_t)255;
    return p;
  };
  const int nb_n  = (N + 255) / 256;
  const int nb_e  = (E + 1023) / 1024;
  unsigned* scores = (unsigned*)carve((size_t)N * 4);
  size_t zero_begin = off;
  unsigned* hist1   = (unsigned*)carve((size_t)65536 * 4);
  unsigned* hist2   = (unsigned*)carve((size_t)65536 * 4);
  unsigned* tickets = (unsigned*)carve(4 * 4);   // [0]=node, [1]=edge, [2]=done1, [3]=done2
  unsigned long long* status_n = (unsigned long long*)carve((size_t)nb_n * 8);
  unsigned long long* status_e = (unsigned long long*)carve((size_t)nb_e * 8);
  size_t zero_end = off;
  unsigned* sel    = (unsigned*)carve(64);
  int* map         = (int*)carve((size_t)N * 4);
  (void)ws_size;

  // one memset covers hists + tickets/done counters + lookback status arrays (~540 KB)
  hipMemsetAsync(hist1, 0, zero_end - zero_begin, stream);
  scores_hist_kernel<<<nb_n, 256, 0, stream>>>(x, w, b, N, F, scores, hist1,
                                               q, sel, tickets + 2);
  hist2_kernel<<<nb_n, 256, 0, stream>>>(scores, N, sel, hist2, sel + 2, tickets + 3);
  node_compact<<<nb_n, 256, 0, stream>>>(scores, sel, x, N, F, n_keep, tickets + 0,
                                         status_n, map, out + o_pool, out + o_newx);
  edge_compact<<<nb_e, 256, 0, stream>>>(ei, map, E, Ek, Fe, attr, tickets + 1, status_e,
                                         out, o_ei, o_eio, o_attr, o_pe);
}